// Round 6
// baseline (371.355 us; speedup 1.0000x reference)
//
#include <hip/hip_runtime.h>
#include <hip/hip_bf16.h>

typedef __attribute__((ext_vector_type(8))) short bf16x8;
typedef __attribute__((ext_vector_type(4))) float f32x4;

static __device__ __forceinline__ short b16(float f) {
    __hip_bfloat16 h = __float2bfloat16(f);
    return *reinterpret_cast<short*>(&h);
}

// ---------------------------------------------------------------- prep kernel
// weight transposes/cvt (q pre-scaled), scaled qkv bias, and the combined
// (rel-pos bias + mask) table in MFMA C-fragment order:
// cbt[w][h][rt][ct][lane] = f32x4 over reg, -1e30 baked into m>=49 pad.
__global__ void k_prep(const float* __restrict__ qkv_w, const float* __restrict__ qkv_b,
                       const float* __restrict__ proj_w, const float* __restrict__ bias_table,
                       const float* __restrict__ mask,
                       __hip_bfloat16* __restrict__ qwT, __hip_bfloat16* __restrict__ pwT,
                       float* __restrict__ qb_s, float* __restrict__ cbt) {
    const float scale = 0.17677669529663687f; // 32^-0.5
    const int P1 = 768 * 256, P2 = P1 + 256 * 256, P3 = P2 + 768, P4 = P3 + 64 * 8 * 4 * 4 * 64;
    int i = blockIdx.x * 256 + threadIdx.x;
    if (i < P1) {
        int nc = i >> 8, kc = i & 255;
        float v = qkv_w[kc * 768 + nc];
        if (nc < 256) v *= scale;
        qwT[i] = __float2bfloat16(v);
    } else if (i < P2) {
        int j = i - P1;
        int nc = j >> 8, kc = j & 255;
        pwT[j] = __float2bfloat16(proj_w[kc * 256 + nc]);
    } else if (i < P3) {
        int j = i - P2;
        qb_s[j] = qkv_b[j] * (j < 256 ? scale : 1.f);
    } else if (i < P4) {
        int j = i - P3;                       // [w][h][rt][ct][lane]
        int w = j >> 13;
        int h = (j >> 10) & 7;
        int rt = (j >> 8) & 3;
        int ct = (j >> 6) & 3;
        int lane = j & 63;
        int m = ct * 16 + (lane & 15);
        f32x4 v;
#pragma unroll
        for (int reg = 0; reg < 4; ++reg) {
            int n = rt * 16 + 4 * (lane >> 4) + reg;
            float val;
            if (m >= 49) val = -1e30f;
            else if (n >= 49) val = 0.f;
            else {
                int i1 = n / 7, j1 = n % 7, i2 = m / 7, j2 = m % 7;
                int rpi = (i1 - i2 + 6) * 13 + (j1 - j2 + 6);
                val = bias_table[rpi * 8 + h] + mask[(w * 49 + n) * 49 + m];
            }
            v[reg] = val;
        }
        ((f32x4*)cbt)[j] = v;
    }
}

// ---------------------------------------------------------------- fused per-window kernel
// One block per window (2048 blocks, 512 threads = 8 waves, wave = head).
// LDS regions (bytes, total 151040):
//  region0 [0, 50176):       xs[64][256] bf16 slot-swizzled (32768)  ->then  pl8: 8 x 6272 (49x128B, XOR swz)
//  region1 [50176, 114176):  qk8: 8 x {qs 49x80B, ks @+4000}        ->then  att_s[64][256] swizzled (32768)
//  region2 [114176, 151040): vt8: 8 x (32 x 144B)  -- ALL 64 m-rows written (0 for m>=49):
//                            PV reads m up to 63 and 0*NaN=NaN if left uninitialized.
#define XS_OFF    0
#define PL_OFF(h) ((h) * 6272)
#define QK_OFF    50176
#define QS(h)     (QK_OFF + (h) * 8000)
#define KS(h)     (QK_OFF + (h) * 8000 + 4000)
#define AS_OFF    QK_OFF
#define VT(h)     (114176 + (h) * 4608)
#define LDS_TOTAL 151040

__global__ __launch_bounds__(512, 2)
void win_fused(const float* __restrict__ x,
               const __hip_bfloat16* __restrict__ qwT,   // [768][256] bf16 (q part pre-scaled)
               const __hip_bfloat16* __restrict__ pwT,   // [256][256] bf16
               const float* __restrict__ qb_s,           // [768] (q part pre-scaled)
               const float* __restrict__ proj_b,         // [256]
               const float* __restrict__ cbt,            // [64][8][4][4][64][4] f32
               float* __restrict__ out) {
    __shared__ alignas(16) char lds[LDS_TOTAL];
    const int b = blockIdx.x;
    const int tid = threadIdx.x;
    const int h = tid >> 6, lane = tid & 63, g = lane >> 4, c0 = lane & 15;

    // ---- stage x window -> xs bf16 (slot-XOR swizzled rows; rows 49..63 left as garbage,
    // their downstream outputs are clamped/discarded: MFMA C-row n depends only on A-row n)
    const float* xw = x + (size_t)b * 12544;
    for (int i = tid; i < 3136; i += 512) {
        int row = i >> 6, col4 = i & 63;
        float4 v = *(const float4*)(xw + row * 256 + col4 * 4);
        union { unsigned long long u; short s[4]; } o;
        o.s[0] = b16(v.x); o.s[1] = b16(v.y); o.s[2] = b16(v.z); o.s[3] = b16(v.w);
        int byte = row * 512 + (((col4 >> 1) ^ (row & 7)) << 4) + (col4 & 1) * 8;
        *(unsigned long long*)(lds + byte) = o.u;
    }
    __syncthreads();  // #1: xs visible to all waves

    // ---- phase A: per-head q/k/v GEMM  (C[64][32] each, K=256)
    f32x4 acc[3][4][2];
#pragma unroll
    for (int q3 = 0; q3 < 3; ++q3)
#pragma unroll
        for (int rt = 0; rt < 4; ++rt)
#pragma unroll
            for (int ct2 = 0; ct2 < 2; ++ct2)
#pragma unroll
                for (int r = 0; r < 4; ++r) acc[q3][rt][ct2][r] = 0.f;

#pragma unroll
    for (int kt = 0; kt < 8; ++kt) {
        bf16x8 af[4];
#pragma unroll
        for (int rt = 0; rt < 4; ++rt) {
            int row = rt * 16 + c0;
            af[rt] = *(const bf16x8*)(lds + row * 512 + (((kt * 4 + g) ^ (c0 & 7)) << 4));
        }
#pragma unroll
        for (int q3 = 0; q3 < 3; ++q3) {
#pragma unroll
            for (int ct2 = 0; ct2 < 2; ++ct2) {
                bf16x8 bw = *(const bf16x8*)(qwT + (size_t)(q3 * 256 + h * 32 + ct2 * 16 + c0) * 256
                                             + kt * 32 + g * 8);
#pragma unroll
                for (int rt = 0; rt < 4; ++rt)
                    acc[q3][rt][ct2] = __builtin_amdgcn_mfma_f32_16x16x32_bf16(
                        af[rt], bw, acc[q3][rt][ct2], 0, 0, 0);
            }
        }
    }
    // bias add + write q/k/v to per-head LDS in fragment-friendly layouts.
    // V: write ALL 64 rows (bf16 zero for n>=49) so PV's k-range 0..63 reads no garbage.
#pragma unroll
    for (int q3 = 0; q3 < 3; ++q3) {
#pragma unroll
        for (int ct2 = 0; ct2 < 2; ++ct2) {
            float bias = qb_s[q3 * 256 + h * 32 + ct2 * 16 + c0];
            int d0 = ct2 * 16 + c0;
#pragma unroll
            for (int rt = 0; rt < 4; ++rt) {
#pragma unroll
                for (int reg = 0; reg < 4; ++reg) {
                    int n = rt * 16 + 4 * g + reg;
                    if (q3 == 2) {
                        short sv = (n < 49) ? b16(acc[q3][rt][ct2][reg] + bias) : (short)0;
                        *(short*)(lds + VT(h) + d0 * 144 + n * 2) = sv;
                    } else if (n < 49) {
                        short sv = b16(acc[q3][rt][ct2][reg] + bias);
                        if (q3 == 0) *(short*)(lds + QS(h) + n * 80 + d0 * 2) = sv;
                        else         *(short*)(lds + KS(h) + n * 80 + d0 * 2) = sv;
                    }
                }
            }
        }
    }
    __syncthreads();  // #2: all waves done reading xs -> pl region reusable

    // ---- QK^T + softmax (per wave, own head)
    bf16x8 qf[4], kf[4];
#pragma unroll
    for (int t = 0; t < 4; ++t) {
        int n = t * 16 + c0;
        int nc = n < 49 ? n : 48;   // clamped dup rows; killed by cbt / discarded
        qf[t] = *(const bf16x8*)(lds + QS(h) + nc * 80 + g * 16);
        kf[t] = *(const bf16x8*)(lds + KS(h) + nc * 80 + g * 16);
    }
    const f32x4* cbb = (const f32x4*)cbt + ((size_t)((b & 63) * 8 + h)) * 1024;
    const f32x4 zf = {0.f, 0.f, 0.f, 0.f};

#pragma unroll
    for (int rt = 0; rt < 4; ++rt) {
        f32x4 cb[4];
#pragma unroll
        for (int ct = 0; ct < 4; ++ct) cb[ct] = cbb[(rt * 4 + ct) * 64 + lane];
        f32x4 s[4];
        __builtin_amdgcn_s_setprio(1);
#pragma unroll
        for (int ct = 0; ct < 4; ++ct)
            s[ct] = __builtin_amdgcn_mfma_f32_16x16x32_bf16(qf[rt], kf[ct], zf, 0, 0, 0);
        __builtin_amdgcn_s_setprio(0);
#pragma unroll
        for (int ct = 0; ct < 4; ++ct)
#pragma unroll
            for (int reg = 0; reg < 4; ++reg) s[ct][reg] += cb[ct][reg];
        // rows n = rt*16 + 4g + reg ; cols m = ct*16 + c0
#pragma unroll
        for (int reg = 0; reg < 4; ++reg) {
            int n = rt * 16 + 4 * g + reg;
            float mx = fmaxf(fmaxf(s[0][reg], s[1][reg]), fmaxf(s[2][reg], s[3][reg]));
            mx = fmaxf(mx, __shfl_xor(mx, 1));
            mx = fmaxf(mx, __shfl_xor(mx, 2));
            mx = fmaxf(mx, __shfl_xor(mx, 4));
            mx = fmaxf(mx, __shfl_xor(mx, 8));
            float sum = 0.f;
#pragma unroll
            for (int ct = 0; ct < 4; ++ct) {
                float e = __expf(s[ct][reg] - mx);
                s[ct][reg] = e;
                sum += e;
            }
            sum += __shfl_xor(sum, 1);
            sum += __shfl_xor(sum, 2);
            sum += __shfl_xor(sum, 4);
            sum += __shfl_xor(sum, 8);
            float inv = 1.f / sum;
            if (n < 49) {
#pragma unroll
                for (int ct = 0; ct < 4; ++ct) {
                    int m = ct * 16 + c0;
                    int byte = (n * 128 + m * 2) ^ ((n & 7) << 4);
                    *(short*)(lds + PL_OFF(h) + byte) = b16(s[ct][reg] * inv);
                }
            }
        }
    }
    __syncthreads();  // #3: all waves past QK^T reads -> att_s region reusable

    // ---- PV (per wave, own head)
    f32x4 o[4][2];
#pragma unroll
    for (int rt = 0; rt < 4; ++rt)
#pragma unroll
        for (int ci = 0; ci < 2; ++ci)
#pragma unroll
            for (int r = 0; r < 4; ++r) o[rt][ci][r] = 0.f;
#pragma unroll
    for (int kt2 = 0; kt2 < 2; ++kt2) {
        bf16x8 pa[4], vb[2];
#pragma unroll
        for (int rt = 0; rt < 4; ++rt) {
            int row = rt * 16 + c0;
            int rc = row < 49 ? row : 48;
            int byte = rc * 128 + (((kt2 * 4 + g) ^ (rc & 7)) << 4);
            pa[rt] = *(const bf16x8*)(lds + PL_OFF(h) + byte);
        }
#pragma unroll
        for (int ci = 0; ci < 2; ++ci)
            vb[ci] = *(const bf16x8*)(lds + VT(h) + (ci * 16 + c0) * 144 + (kt2 * 32 + g * 8) * 2);
        __builtin_amdgcn_s_setprio(1);
#pragma unroll
        for (int rt = 0; rt < 4; ++rt)
#pragma unroll
            for (int ci = 0; ci < 2; ++ci)
                o[rt][ci] = __builtin_amdgcn_mfma_f32_16x16x32_bf16(pa[rt], vb[ci], o[rt][ci], 0, 0, 0);
        __builtin_amdgcn_s_setprio(0);
    }
    // write att rows (C-layout -> swizzled att_s[n][col])
#pragma unroll
    for (int rt = 0; rt < 4; ++rt) {
#pragma unroll
        for (int ci = 0; ci < 2; ++ci) {
#pragma unroll
            for (int reg = 0; reg < 4; ++reg) {
                int n = rt * 16 + 4 * g + reg;
                if (n < 49) {
                    int col = h * 32 + ci * 16 + c0;
                    *(short*)(lds + AS_OFF + n * 512 + (((col >> 3) ^ (n & 7)) << 4) + (col & 7) * 2)
                        = b16(o[rt][ci][reg]);
                }
            }
        }
    }
    __syncthreads();  // #4: att_s complete (cross-wave: proj reads all heads' cols)

    // ---- proj GEMM: out[49][256] = att_s @ pwT^T + proj_b ; wave h -> cols h*32..h*32+31
    f32x4 po[4][2];
#pragma unroll
    for (int rt = 0; rt < 4; ++rt)
#pragma unroll
        for (int ct2 = 0; ct2 < 2; ++ct2)
#pragma unroll
            for (int r = 0; r < 4; ++r) po[rt][ct2][r] = 0.f;
#pragma unroll
    for (int kt = 0; kt < 8; ++kt) {
        bf16x8 paf[4], pb[2];
#pragma unroll
        for (int rt = 0; rt < 4; ++rt) {
            int row = rt * 16 + c0;
            paf[rt] = *(const bf16x8*)(lds + AS_OFF + row * 512 + (((kt * 4 + g) ^ (c0 & 7)) << 4));
        }
#pragma unroll
        for (int ct2 = 0; ct2 < 2; ++ct2)
            pb[ct2] = *(const bf16x8*)(pwT + (size_t)(h * 32 + ct2 * 16 + c0) * 256 + kt * 32 + g * 8);
#pragma unroll
        for (int rt = 0; rt < 4; ++rt)
#pragma unroll
            for (int ct2 = 0; ct2 < 2; ++ct2)
                po[rt][ct2] = __builtin_amdgcn_mfma_f32_16x16x32_bf16(
                    paf[rt], pb[ct2], po[rt][ct2], 0, 0, 0);
    }
    float* ob = out + (size_t)b * 12544;
    float pbias[2];
#pragma unroll
    for (int ct2 = 0; ct2 < 2; ++ct2) pbias[ct2] = proj_b[h * 32 + ct2 * 16 + c0];
#pragma unroll
    for (int rt = 0; rt < 4; ++rt) {
#pragma unroll
        for (int ct2 = 0; ct2 < 2; ++ct2) {
#pragma unroll
            for (int reg = 0; reg < 4; ++reg) {
                int n = rt * 16 + 4 * g + reg;
                if (n < 49)
                    ob[(size_t)n * 256 + h * 32 + ct2 * 16 + c0] = po[rt][ct2][reg] + pbias[ct2];
            }
        }
    }
}

// ---------------------------------------------------------------- host
extern "C" void kernel_launch(void* const* d_in, const int* in_sizes, int n_in,
                              void* d_out, int out_size, void* d_ws, size_t ws_size,
                              hipStream_t stream) {
    const float* x          = (const float*)d_in[0];
    const float* mask       = (const float*)d_in[1];
    const float* qkv_w      = (const float*)d_in[2];
    const float* qkv_b      = (const float*)d_in[3];
    const float* proj_w     = (const float*)d_in[4];
    const float* proj_b     = (const float*)d_in[5];
    const float* bias_table = (const float*)d_in[6];

    const int C = 256, NN = 49;
    const int M  = in_sizes[0] / C;  // 100352
    const int B_ = M / NN;           // 2048

    char* ws = (char*)d_ws;
    __hip_bfloat16* qwT = (__hip_bfloat16*)ws;                       // [768][256]
    size_t off = (size_t)768 * 256 * 2;
    __hip_bfloat16* pwT = (__hip_bfloat16*)(ws + off); off += (size_t)256 * 256 * 2;
    float* qb_s = (float*)(ws + off); off += (size_t)768 * 4;
    float* cbt  = (float*)(ws + off); off += (size_t)64 * 8 * 4096 * 4;  // 8 MB

    int prep_total = 768 * 256 + 256 * 256 + 768 + 64 * 8 * 4 * 4 * 64;
    k_prep<<<(prep_total + 255) / 256, 256, 0, stream>>>(qkv_w, qkv_b, proj_w, bias_table, mask,
                                                         qwT, pwT, qb_s, cbt);
    win_fused<<<B_, 512, 0, stream>>>(x, qwT, pwT, qb_s, proj_b, cbt, (float*)d_out);
}